// Round 17
// baseline (79.801 us; speedup 1.0000x reference)
//
#include <hip/hip_runtime.h>
#include <cstdint>

typedef unsigned int u32;
typedef unsigned long long u64;
typedef __attribute__((ext_vector_type(8))) short short8;
typedef __attribute__((ext_vector_type(4))) float f32x4;

#define DIM    10000
#define NCLS   100
#define BATCH  4096
#define NST    313          // ceil(10000/32) K-steps of 32
#define NFR    7            // 7 B-frags x 16 cols = 112 padded classes
#define BCLS   112
#define KPW    39           // K-steps per wave (wave 7 gets 40)

// matches = DIM - asum[c] - qsum[b] + 2 * (q . a^T)   — all exact ints in f32.
// bf16 conversion of {0.0, 1.0} = top 16 bits of the f32 (exact).
// Padded class 100 = all-ones row -> its MFMA column yields qsum[b] for free.
// Classes 101..111 are zeros (ignored). K >= DIM is zero on the B side, so
// clamped A loads contribute nothing.

__device__ __forceinline__ short bf16hi(float x) {
    return (short)(__float_as_uint(x) >> 16);
}

// ---- asum[c] = sum_k a[c][k] (one wave per class) ----
__global__ __launch_bounds__(256) void asum_k(const float* __restrict__ a,
                                              float* __restrict__ asum) {
    const int lane = threadIdx.x & 63;
    const int c    = blockIdx.x * 4 + (threadIdx.x >> 6);   // 0..99
    const float4* ar = (const float4*)(a + (size_t)c * DIM);
    float s = 0.f;
    for (int i = lane; i < DIM / 4; i += 64) {
        const float4 v = ar[i];
        s += v.x + v.y + v.z + v.w;
    }
#pragma unroll
    for (int off = 32; off >= 1; off >>= 1) s += __shfl_down(s, off);
    if (lane == 0) asum[c] = s;                             // exact integer
}

// ---- pack a -> Bf[ks][f][lane] = uint4 (8 bf16, frag-ordered) ----
// wave u = ks*NFR + f; lane l: col = 16f + (l&15), k = 32ks + 8*(l>>4) + j.
__global__ __launch_bounds__(256) void pack_b(const float* __restrict__ a,
                                              uint4* __restrict__ Bf) {
    const int lane = threadIdx.x & 63;
    const int u    = blockIdx.x * 4 + (threadIdx.x >> 6);
    if (u >= NST * NFR) return;
    const int ks  = u / NFR;
    const int f   = u - ks * NFR;
    const int cls = 16 * f + (lane & 15);
    const int k0  = 32 * ks + ((lane >> 4) << 3);

    short sv[8];
    if (cls < NCLS) {
        const float* ar = a + (size_t)cls * DIM;
#pragma unroll
        for (int j = 0; j < 8; ++j) {
            const int k   = k0 + j;
            const float v = (k < DIM) ? ar[k] : 0.f;
            sv[j] = bf16hi(v);
        }
    } else if (cls == NCLS) {                               // ones-class -> qsum
#pragma unroll
        for (int j = 0; j < 8; ++j)
            sv[j] = (k0 + j < DIM) ? (short)0x3F80 : (short)0;
    } else {
#pragma unroll
        for (int j = 0; j < 8; ++j) sv[j] = 0;
    }
    uint4 w;
    w.x = (u32)(unsigned short)sv[0] | ((u32)(unsigned short)sv[1] << 16);
    w.y = (u32)(unsigned short)sv[2] | ((u32)(unsigned short)sv[3] << 16);
    w.z = (u32)(unsigned short)sv[4] | ((u32)(unsigned short)sv[5] << 16);
    w.w = (u32)(unsigned short)sv[6] | ((u32)(unsigned short)sv[7] << 16);
    Bf[(size_t)u * 64 + lane] = w;                          // coalesced 1 KB
}

// ---- main: 256 blocks x 512 thr; block = 16 rows; wave = K-slice ----
__global__ __launch_bounds__(512) void mfma_main(const float* __restrict__ q,
                                                 const uint4* __restrict__ Bf,
                                                 const float* __restrict__ asum,
                                                 float* __restrict__ out) {
    __shared__ float P[8][16][BCLS];                        // 57,344 B
    const int lane = threadIdx.x & 63;
    const int wv   = threadIdx.x >> 6;                      // 0..7
    const int r0   = blockIdx.x * 16;
    const float* qr = q + (size_t)(r0 + (lane & 15)) * DIM; // A row = lane&15
    const int kg8   = (lane >> 4) << 3;                     // A k-group offset
    const int kbeg  = wv * KPW;
    const int cnt   = (wv == 7) ? (NST - 7 * KPW) : KPW;    // 40 for wave 7

    f32x4 acc[NFR];
#pragma unroll
    for (int f = 0; f < NFR; ++f) acc[f] = (f32x4){0.f, 0.f, 0.f, 0.f};

    const uint4* bp = Bf + (size_t)kbeg * (NFR * 64) + lane;
    for (int s = 0; s < cnt; ++s) {
        int ka = 32 * (kbeg + s) + kg8;
        ka = (ka <= DIM - 8) ? ka : (DIM - 8);              // clamp; B zeros kill pad
        const float4 a0 = *(const float4*)(qr + ka);
        const float4 a1 = *(const float4*)(qr + ka + 4);
        short8 af;
        af[0] = bf16hi(a0.x); af[1] = bf16hi(a0.y);
        af[2] = bf16hi(a0.z); af[3] = bf16hi(a0.w);
        af[4] = bf16hi(a1.x); af[5] = bf16hi(a1.y);
        af[6] = bf16hi(a1.z); af[7] = bf16hi(a1.w);
#pragma unroll
        for (int f = 0; f < NFR; ++f) {
            union { uint4 u; short8 s; } bu;
            bu.u = bp[f * 64];                              // coalesced 1 KB
            acc[f] = __builtin_amdgcn_mfma_f32_16x16x32_bf16(af, bu.s, acc[f],
                                                             0, 0, 0);
        }
        bp += NFR * 64;
    }

    // C/D layout (m89): col = lane&15, row = (lane>>4)*4 + reg
    const int orow = (lane >> 4) << 2;
    const int ocol = lane & 15;
#pragma unroll
    for (int f = 0; f < NFR; ++f)
#pragma unroll
        for (int r = 0; r < 4; ++r)
            P[wv][orow + r][16 * f + ocol] = acc[f][r];
    __syncthreads();

    for (int t = threadIdx.x; t < 16 * NCLS; t += 512) {
        const int row = t / NCLS;
        const int col = t - row * NCLS;
        float s2 = 0.f, rs = 0.f;
#pragma unroll
        for (int w = 0; w < 8; ++w) {
            s2 += P[w][row][col];
            rs += P[w][row][NCLS];                          // ones-class = qsum
        }
        out[(size_t)(r0 + row) * NCLS + col] =
            (float)DIM - asum[col] - rs + 2.f * s2;         // exact ints
    }
}

extern "C" void kernel_launch(void* const* d_in, const int* in_sizes, int n_in,
                              void* d_out, int out_size, void* d_ws, size_t ws_size,
                              hipStream_t stream) {
    const float* q = (const float*)d_in[0];   // [4096, 10000] f32 {0,1}
    const float* a = (const float*)d_in[1];   // [100, 10000]  f32 {0,1}
    float* out = (float*)d_out;               // [4096, 100]   f32

    // ws: asum f32[128] at 0; Bf at 4 KiB (313*7*64*16 = 2,243,584 B)
    float* asum = (float*)d_ws;
    uint4* Bf   = (uint4*)((char*)d_ws + 4096);

    asum_k<<<25, 256, 0, stream>>>(a, asum);
    pack_b<<<(NST * NFR + 3) / 4, 256, 0, stream>>>(a, Bf);
    mfma_main<<<BATCH / 16, 512, 0, stream>>>(q, Bf, asum, out);
}

// Round 18
// 34.967 us; speedup vs baseline: 2.2822x; 2.2822x over previous
//
#include <hip/hip_runtime.h>
#include <cstdint>

typedef unsigned long long u64;
typedef unsigned int u32;

#define DIM    10000
#define NCLS   100
#define BATCH  4096
#define F4ROW  2500          // float4s per input row
#define NCH    40            // 256-dim chunks per row (chunk 39 partial)

// Bit order (identical for q and am): chunk C covers dims [C*256, C*256+256);
// word j of chunk C, bit i <- dim C*256 + 4i + j (ballot lane i, float4 elem j).
// apT2 layout: [wpair = 2C + s][class]; s=0 holds (b0,b1), s=1 holds (b2,b3).
// Pad dims (>= DIM) give 0-bits on BOTH operands -> XOR contributes nothing.

// ---- pack am -> apT2, PARALLEL: one wave per (chunk, class) ----
// grid (10, 100) x 256 threads = 4000 waves, ONE iteration each (no serial
// latency chain -- the old 100-wave/40-iter version was ~15-20 us of pure
// HBM round-trip latency on an otherwise idle machine).
__global__ __launch_bounds__(256) void pack_a_p(const float* __restrict__ a,
                                                ulonglong2* __restrict__ apT2) {
    const int lane = threadIdx.x & 63;
    const int C    = blockIdx.x * 4 + (threadIdx.x >> 6);   // chunk 0..39
    const int r    = blockIdx.y;                            // class 0..99
    const int d0   = C * 256 + lane * 4;
    float4 v = make_float4(0.f, 0.f, 0.f, 0.f);
    if (d0 < DIM) v = *(const float4*)(a + (size_t)r * DIM + d0);
    const u64 b0 = __ballot(v.x > 0.5f);
    const u64 b1 = __ballot(v.y > 0.5f);
    const u64 b2 = __ballot(v.z > 0.5f);
    const u64 b3 = __ballot(v.w > 0.5f);
    if (lane < 2) {
        ulonglong2 u;
        u.x = lane ? b2 : b0;
        u.y = lane ? b3 : b1;
        apT2[(size_t)(2 * C + lane) * NCLS + r] = u;        // wpair = 2C+lane
    }
}

// ---- fused v4 (VERBATIM round 12 — experiment control) ----
__global__ __launch_bounds__(256) void fused_v4(const float* __restrict__ q,
                                                const ulonglong2* __restrict__ apT2,
                                                float* __restrict__ out) {
    __shared__ int part[4][4][128];                         // [wave][row][class]
    const int lane = threadIdx.x & 63;
    const int wv   = threadIdx.x >> 6;                      // 0..3 = chunk group
    const int r0   = blockIdx.x * 4;
    const int clsA = lane;
    const int clsB = 64 + (lane < NCLS - 64 ? lane : NCLS - 65);

    u32 accA[4] = {0, 0, 0, 0};
    u32 accB[4] = {0, 0, 0, 0};

    const int Cbeg = wv * 10;
    const int Cfull = (wv == 3) ? 39 : Cbeg + 10;           // chunk 39 handled apart

    for (int C = Cbeg; C < Cfull; ++C) {
        float4 v[4];
#pragma unroll
        for (int ri = 0; ri < 4; ++ri)
            v[ri] = *(const float4*)(q + (size_t)(r0 + ri) * DIM
                                       + (size_t)(C * 64 + lane) * 4);
        const ulonglong2* wp0 = apT2 + (size_t)(2 * C) * NCLS;
        const ulonglong2* wp1 = wp0 + NCLS;
        const ulonglong2 aA0 = wp0[clsA];
        const ulonglong2 aA1 = wp1[clsA];
        const ulonglong2 aB0 = wp0[clsB];
        const ulonglong2 aB1 = wp1[clsB];
#pragma unroll
        for (int ri = 0; ri < 4; ++ri) {
            const u64 b0 = __ballot(v[ri].x > 0.5f);
            const u64 b1 = __ballot(v[ri].y > 0.5f);
            const u64 b2 = __ballot(v[ri].z > 0.5f);
            const u64 b3 = __ballot(v[ri].w > 0.5f);
            accA[ri] += (u32)(__popcll(b0 ^ aA0.x) + __popcll(b1 ^ aA0.y) +
                              __popcll(b2 ^ aA1.x) + __popcll(b3 ^ aA1.y));
            accB[ri] += (u32)(__popcll(b0 ^ aB0.x) + __popcll(b1 ^ aB0.y) +
                              __popcll(b2 ^ aB1.x) + __popcll(b3 ^ aB1.y));
        }
    }

    if (wv == 3) {                                          // chunk 39: partial
        const int C    = 39;
        const int idx  = C * 64 + lane;
        const int lidx = idx < F4ROW ? idx : F4ROW - 1;
        const bool ok  = idx < F4ROW;
        const ulonglong2* wp0 = apT2 + (size_t)(2 * C) * NCLS;
        const ulonglong2* wp1 = wp0 + NCLS;
        const ulonglong2 aA0 = wp0[clsA];
        const ulonglong2 aA1 = wp1[clsA];
        const ulonglong2 aB0 = wp0[clsB];
        const ulonglong2 aB1 = wp1[clsB];
#pragma unroll
        for (int ri = 0; ri < 4; ++ri) {
            const float4 v = *(const float4*)(q + (size_t)(r0 + ri) * DIM
                                                + (size_t)lidx * 4);
            const u64 b0 = __ballot(ok && (v.x > 0.5f));
            const u64 b1 = __ballot(ok && (v.y > 0.5f));
            const u64 b2 = __ballot(ok && (v.z > 0.5f));
            const u64 b3 = __ballot(ok && (v.w > 0.5f));
            accA[ri] += (u32)(__popcll(b0 ^ aA0.x) + __popcll(b1 ^ aA0.y) +
                              __popcll(b2 ^ aA1.x) + __popcll(b3 ^ aA1.y));
            accB[ri] += (u32)(__popcll(b0 ^ aB0.x) + __popcll(b1 ^ aB0.y) +
                              __popcll(b2 ^ aB1.x) + __popcll(b3 ^ aB1.y));
        }
    }

#pragma unroll
    for (int ri = 0; ri < 4; ++ri) {
        part[wv][ri][lane] = (int)accA[ri];
        if (lane < NCLS - 64) part[wv][ri][64 + lane] = (int)accB[ri];
    }
    __syncthreads();

    const int tid = threadIdx.x;
#pragma unroll
    for (int o = tid; o < 4 * NCLS; o += 256) {
        const int ri  = o / NCLS;
        const int cls = o - ri * NCLS;
        const int s = part[0][ri][cls] + part[1][ri][cls] +
                      part[2][ri][cls] + part[3][ri][cls];
        out[(size_t)(r0 + ri) * NCLS + cls] = (float)(DIM - s);
    }
}

extern "C" void kernel_launch(void* const* d_in, const int* in_sizes, int n_in,
                              void* d_out, int out_size, void* d_ws, size_t ws_size,
                              hipStream_t stream) {
    const float* q = (const float*)d_in[0];   // [4096, 10000] f32 {0,1}
    const float* a = (const float*)d_in[1];   // [100, 10000]  f32 {0,1}
    float* out = (float*)d_out;               // [4096, 100]   f32

    // ws: apT2 only (80 wpairs * 100 classes * 16 B = 128,000 B)
    ulonglong2* apT2 = (ulonglong2*)d_ws;

    pack_a_p<<<dim3(10, NCLS), 256, 0, stream>>>(a, apT2);
    fused_v4<<<BATCH / 4, 256, 0, stream>>>(q, apT2, out);
}